// Round 4
// baseline (122.437 us; speedup 1.0000x reference)
//
#include <hip/hip_runtime.h>

// Geometry: GROUP = 256 rows per fused block. n assumed multiple of 4 (actual: 1<<20).
#define GROUP 256

typedef float f4 __attribute__((ext_vector_type(4)));   // native vec type for NT builtins

// ---------- Pass 1: count ones per 256-elem group ----------
// Block = 256 threads processes 4096 int4 (16384 elems = 64 groups).
// Iteration it, wave w (=t/64) covers exactly group blk*64 + it*4 + w.
__global__ __launch_bounds__(256)
void dps_count(const int* __restrict__ parts, int n, int* __restrict__ group_sums) {
    const int t = threadIdx.x;
    const int w = t >> 6;
    const int n4 = n >> 2;
    const int4* p4 = reinterpret_cast<const int4*>(parts);
    #pragma unroll
    for (int it = 0; it < 16; ++it) {
        int i4 = blockIdx.x * 4096 + it * 256 + t;
        int s = 0;
        if (i4 < n4) {
            int4 v = p4[i4];
            s = v.x + v.y + v.z + v.w;
        }
        #pragma unroll
        for (int off = 32; off >= 1; off >>= 1) s += __shfl_down(s, off, 64);
        if ((t & 63) == 0) {
            int g = blockIdx.x * 64 + it * 4 + w;
            int ngroups = (n + GROUP - 1) / GROUP;
            if (g < ngroups) group_sums[g] = s;
        }
    }
}

// ---------- Pass 2: exclusive scan of group_sums (nb <= 4096), single block ----------
__global__ __launch_bounds__(256)
void dps_scan(int* __restrict__ gs, int nb) {
    __shared__ int lds[256];
    const int t = threadIdx.x;
    int v[16];
    int s = 0;
    #pragma unroll
    for (int k = 0; k < 16; ++k) {
        int idx = t * 16 + k;
        v[k] = (idx < nb) ? gs[idx] : 0;
        s += v[k];
    }
    lds[t] = s;
    __syncthreads();
    for (int off = 1; off < 256; off <<= 1) {
        int add = (t >= off) ? lds[t - off] : 0;
        __syncthreads();
        lds[t] += add;
        __syncthreads();
    }
    int run = lds[t] - s;   // exclusive prefix of this thread's chunk
    #pragma unroll
    for (int k = 0; k < 16; ++k) {
        int idx = t * 16 + k;
        if (idx < nb) gs[idx] = run;
        run += v[k];
    }
}

// ---------- Pass 3 (fused): rank + row copy ----------
// Block b handles rows [b*256, b*256+256). 256 threads.
__global__ __launch_bounds__(256)
void dps_fused(const f4* __restrict__ data4,
               const int* __restrict__ parts,
               const int* __restrict__ index0,
               const int* __restrict__ index1,
               const int* __restrict__ group_excl,
               int n,
               f4* __restrict__ out4) {
    __shared__ int lds [256];
    __shared__ int ldsd[256];
    const int t    = threadIdx.x;
    const int base = blockIdx.x * GROUP;
    const int i    = base + t;

    int p = (i < n) ? parts[i] : 0;
    lds[t] = p;
    __syncthreads();
    for (int off = 1; off < 256; off <<= 1) {
        int add = (t >= off) ? lds[t - off] : 0;
        __syncthreads();
        lds[t] += add;
        __syncthreads();
    }
    int ones_excl = group_excl[blockIdx.x] + (lds[t] - p);  // global #ones before i
    if (i < n) {
        ldsd[t] = p ? index1[ones_excl] : index0[i - ones_excl];
    }
    __syncthreads();

    // Copy 256 rows x 256B: iteration it covers rows it*16 .. it*16+15,
    // 16 lanes per row. Coalesced NT reads, scattered 256B NT writes.
    const f4* src = data4 + ((long)base << 4);
    const int q  = t & 15;
    const int r0 = t >> 4;
    if (base + GROUP <= n) {
        #pragma unroll
        for (int it = 0; it < 16; ++it) {
            int r = it * 16 + r0;
            f4 v = __builtin_nontemporal_load(src + (r << 4) + q);
            long dr = (long)ldsd[r];
            __builtin_nontemporal_store(v, out4 + (dr << 4) + q);
        }
    } else {
        for (int it = 0; it < 16; ++it) {
            int r = it * 16 + r0;
            if (base + r < n) {
                f4 v = src[(r << 4) + q];
                out4[((long)ldsd[r] << 4) + q] = v;
            }
        }
    }
}

extern "C" void kernel_launch(void* const* d_in, const int* in_sizes, int n_in,
                              void* d_out, int out_size, void* d_ws, size_t ws_size,
                              hipStream_t stream) {
    const float* data   = (const float*)d_in[0];
    const int*   parts  = (const int*)d_in[1];
    const int*   index0 = (const int*)d_in[2];
    const int*   index1 = (const int*)d_in[3];
    const int n = in_sizes[1];

    int* group_sums = (int*)d_ws;                    // ngroups ints (<= 4096 for n=1<<20)

    const int ngroups = (n + GROUP - 1) / GROUP;     // 4096
    const int cblocks = (n / 4 + 4095) / 4096;       // 64 count blocks

    dps_count<<<cblocks, 256, 0, stream>>>(parts, n, group_sums);
    dps_scan <<<1,       256, 0, stream>>>(group_sums, ngroups);
    dps_fused<<<ngroups, 256, 0, stream>>>((const f4*)data, parts, index0, index1,
                                           group_sums, n, (f4*)d_out);
}

// Round 6
// 101.338 us; speedup vs baseline: 1.2082x; 1.2082x over previous
//
#include <hip/hip_runtime.h>

#define SCAN_BLOCK 256
#define EPT 16                      // partition elements per thread
#define CHUNK (SCAN_BLOCK * EPT)    // 4096 elements per block

typedef float f4 __attribute__((ext_vector_type(4)));   // native vec type for NT builtins

// ---------- Pass 1: count ones per chunk ----------
__global__ __launch_bounds__(SCAN_BLOCK)
void dps_count(const int* __restrict__ parts, int n, int* __restrict__ block_sums) {
    const int t  = threadIdx.x;
    const int e0 = blockIdx.x * CHUNK + t * EPT;
    int s = 0;
    if (e0 + EPT <= n) {
        const int4* p4 = reinterpret_cast<const int4*>(parts + e0);
        #pragma unroll
        for (int k = 0; k < EPT / 4; ++k) {
            int4 v = p4[k];
            s += v.x + v.y + v.z + v.w;
        }
    } else {
        for (int j = 0; j < EPT; ++j) {
            int i = e0 + j;
            if (i < n) s += parts[i];
        }
    }
    #pragma unroll
    for (int off = 32; off >= 1; off >>= 1) s += __shfl_down(s, off, 64);
    __shared__ int lds[SCAN_BLOCK / 64];
    if ((t & 63) == 0) lds[t >> 6] = s;
    __syncthreads();
    if (t == 0) {
        int tot = 0;
        #pragma unroll
        for (int w = 0; w < SCAN_BLOCK / 64; ++w) tot += lds[w];
        block_sums[blockIdx.x] = tot;
    }
}

// ---------- Pass 2: exclusive scan of block sums (nblocks <= SCAN_BLOCK) ----------
__global__ __launch_bounds__(SCAN_BLOCK)
void dps_scan(int* __restrict__ block_sums, int nblocks) {
    __shared__ int lds[SCAN_BLOCK];
    const int t = threadIdx.x;
    int v = (t < nblocks) ? block_sums[t] : 0;
    lds[t] = v;
    __syncthreads();
    for (int off = 1; off < SCAN_BLOCK; off <<= 1) {
        int add = (t >= off) ? lds[t - off] : 0;
        __syncthreads();
        lds[t] += add;
        __syncthreads();
    }
    if (t < nblocks) block_sums[t] = lds[t] - v;   // inclusive -> exclusive
}

// ---------- Pass 3: per-element rank -> dst[i] = output row of input row i ----------
__global__ __launch_bounds__(SCAN_BLOCK)
void dps_rank(const int* __restrict__ parts,
              const int* __restrict__ index0,
              const int* __restrict__ index1,
              const int* __restrict__ block_excl,
              int n, int* __restrict__ dst) {
    const int t  = threadIdx.x;
    const int e0 = blockIdx.x * CHUNK + t * EPT;
    int vals[EPT];
    int s = 0;
    if (e0 + EPT <= n) {
        const int4* p4 = reinterpret_cast<const int4*>(parts + e0);
        #pragma unroll
        for (int k = 0; k < EPT / 4; ++k) {
            int4 v = p4[k];
            vals[k * 4 + 0] = v.x; vals[k * 4 + 1] = v.y;
            vals[k * 4 + 2] = v.z; vals[k * 4 + 3] = v.w;
            s += v.x + v.y + v.z + v.w;
        }
    } else {
        for (int j = 0; j < EPT; ++j) {
            int i = e0 + j;
            vals[j] = (i < n) ? parts[i] : 0;
            s += vals[j];
        }
    }
    __shared__ int lds[SCAN_BLOCK];
    lds[t] = s;
    __syncthreads();
    for (int off = 1; off < SCAN_BLOCK; off <<= 1) {
        int add = (t >= off) ? lds[t - off] : 0;
        __syncthreads();
        lds[t] += add;
        __syncthreads();
    }
    int ones_before = block_excl[blockIdx.x] + (lds[t] - s);
    int dv[EPT];
    #pragma unroll
    for (int j = 0; j < EPT; ++j) {
        int i = e0 + j;
        if (i < n) {
            dv[j] = vals[j] ? index1[ones_before] : index0[i - ones_before];
            ones_before += vals[j];
        }
    }
    if (e0 + EPT <= n) {
        int4* d4 = reinterpret_cast<int4*>(dst + e0);
        #pragma unroll
        for (int k = 0; k < EPT / 4; ++k)
            d4[k] = make_int4(dv[k*4+0], dv[k*4+1], dv[k*4+2], dv[k*4+3]);
    } else {
        for (int j = 0; j < EPT; ++j) {
            int i = e0 + j;
            if (i < n) dst[i] = dv[j];
        }
    }
}

// ---------- Pass 4: scatter copy — NT streaming reads, 4-deep MLP, normal stores ----------
// Block of 512 threads covers one contiguous 2048-f4 slab (128 rows).
// k-slab j: ids [base + k*512, base + k*512 + 512) — fully coalesced reads.
// Stores scattered at 256B row granularity (normal/cached, for write combining).
__global__ __launch_bounds__(512)
void dps_scatter(const f4* __restrict__ data4,
                 const int* __restrict__ dst,
                 f4* __restrict__ out4,
                 long total4) {
    const long base = (long)blockIdx.x * 2048 + threadIdx.x;
    f4   v[4];
    long o[4];
    bool ok[4];
    #pragma unroll
    for (int k = 0; k < 4; ++k) {
        long id = base + (long)k * 512;
        ok[k] = (id < total4);
        if (ok[k]) {
            v[k] = __builtin_nontemporal_load(data4 + id);   // read-once: bypass caches
            int row = (int)(id >> 4);
            int q   = (int)(id & 15);
            o[k] = ((long)dst[row] << 4) + q;                // dst broadcast across 16 lanes
        }
    }
    #pragma unroll
    for (int k = 0; k < 4; ++k)
        if (ok[k]) out4[o[k]] = v[k];                        // normal (cached) store
}

extern "C" void kernel_launch(void* const* d_in, const int* in_sizes, int n_in,
                              void* d_out, int out_size, void* d_ws, size_t ws_size,
                              hipStream_t stream) {
    const float* data   = (const float*)d_in[0];
    const int*   parts  = (const int*)d_in[1];
    const int*   index0 = (const int*)d_in[2];
    const int*   index1 = (const int*)d_in[3];
    const int n = in_sizes[1];

    int* dst        = (int*)d_ws;              // n ints
    int* block_sums = dst + n;                 // nchunks ints

    const int nchunks = (n + CHUNK - 1) / CHUNK;   // 256 for n = 1<<20

    dps_count<<<nchunks, SCAN_BLOCK, 0, stream>>>(parts, n, block_sums);
    dps_scan <<<1,       SCAN_BLOCK, 0, stream>>>(block_sums, nchunks);
    dps_rank <<<nchunks, SCAN_BLOCK, 0, stream>>>(parts, index0, index1, block_sums, n, dst);

    const long total4 = (long)n << 4;                      // n * (64/4)
    const int  blocks = (int)((total4 + 2047) / 2048);     // 8192 for n = 1<<20
    dps_scatter<<<blocks, 512, 0, stream>>>((const f4*)data, dst, (f4*)d_out, total4);
}